// Round 4
// baseline (735.676 us; speedup 1.0000x reference)
//
#include <hip/hip_runtime.h>

// Self-attention (channel-attention variant), B=8 N=4096 C=1024 H=16 D=64.
// FP16 pipeline. cvt(x)->f16; cvt(W*) one dispatch; single QKV GEMM (N=3072,
// Q/K transposed [ch][token], V natural) using 32x32x16 MFMA + XCD-affine block
// remap; attention in 3 stages (partial logits s=16, softmax reduce, PV);
// final GEMM y@Wp^T + bp -> fp32 d_out.

typedef __attribute__((ext_vector_type(4))) float f32x4;
typedef __attribute__((ext_vector_type(16))) float f32x16;
typedef __attribute__((ext_vector_type(8))) _Float16 f16x8;
typedef __attribute__((ext_vector_type(4))) unsigned short u16x4;

__device__ __forceinline__ unsigned short f2h(float f) {
  union { _Float16 h; unsigned short u; } v;
  v.h = (_Float16)f;  // RNE
  return v.u;
}

__global__ void cvt_f32_f16(const float* __restrict__ in, unsigned short* __restrict__ out, int n) {
  int i = (blockIdx.x * blockDim.x + threadIdx.x) * 4;
  if (i >= n) return;
  float4 v = *(const float4*)(in + i);
  u16x4 o;
  o.x = f2h(v.x); o.y = f2h(v.y); o.z = f2h(v.z); o.w = f2h(v.w);
  *(u16x4*)(out + i) = o;
}

// 4 weight matrices (1M elems each) in one dispatch; blockIdx.y selects.
__global__ void cvt4_f32_f16(const float* __restrict__ s0, const float* __restrict__ s1,
                             const float* __restrict__ s2, const float* __restrict__ s3,
                             unsigned short* __restrict__ d0, unsigned short* __restrict__ d1,
                             unsigned short* __restrict__ d2, unsigned short* __restrict__ d3) {
  const float* src; unsigned short* dst;
  switch (blockIdx.y) {
    case 0: src = s0; dst = d0; break;
    case 1: src = s1; dst = d1; break;
    case 2: src = s2; dst = d2; break;
    default: src = s3; dst = d3; break;
  }
  int i = (blockIdx.x * blockDim.x + threadIdx.x) * 4;
  float4 v = *(const float4*)(src + i);
  u16x4 o;
  o.x = f2h(v.x); o.y = f2h(v.y); o.z = f2h(v.z); o.w = f2h(v.w);
  *(u16x4*)(dst + i) = o;
}

// ---------------- GEMM: C = A(MxK) * Bt(NxK)^T, fp16, 128x128 tile, 32x32x16 MFMA ----
#define LDS_LD 68  // epilogue repack stride (u16)
enum { EPI_QKV = 0, EPI_F32_BIAS = 2 };

template <int EPI>
__global__ __launch_bounds__(256, 2) void gemm_bt(const unsigned short* __restrict__ A,
                                                  const unsigned short* __restrict__ Bt,
                                                  void* __restrict__ Cv,
                                                  const float* __restrict__ bias,
                                                  const int M, const int N, const int K) {
  __shared__ unsigned short lds[4 * 64 * LDS_LD];  // staging uses first 8192 u16
  const int tid = threadIdx.x;
  const int wave = tid >> 6, lane = tid & 63;
  const int l31 = lane & 31, hw = lane >> 5;

  // XCD-affine remap: dispatch-consecutive 256 blocks = one n-pass over all 256
  // m-tiles; within it, blocks lin%8==x (round-robin XCD x) get m-range x*32..x*32+31
  // -> each XCD's L2 holds a private 8MB A slice instead of all L2s fetching everything.
  const int lin = blockIdx.y * gridDim.x + blockIdx.x;
  const int g = lin & 255;
  const int mt = (g & 7) * 32 + (g >> 3);
  const int nt = lin >> 8;
  const int m0 = mt * 128, n0 = nt * 128;
  const int mb = (wave & 1) * 64, nb = (wave >> 1) * 64;

  // staging: lane l fetches (row l>>2, 16B-piece (l&3)^((row>>1)&3)) -> XOR swizzle;
  // frag b128 reads land 2 lanes/bank per 16-lane phase (free).
  const int sr = lane >> 2;
  const int sc = (lane & 3) ^ ((sr >> 1) & 3);

  // 32x32 frag offsets: A[m=l31][k=hw*8+j], chunk = 16-row block, slot XOR matches staging
  const int rloc = l31 & 15;
  const int rbase = (l31 >> 4) * 512 + rloc * 32;
  const int sx = (rloc >> 1) & 3;
  int a_off[2][2], b_off[2][2];
#pragma unroll
  for (int t = 0; t < 2; t++)
#pragma unroll
    for (int ks = 0; ks < 2; ks++) {
      const int slot = (ks * 2 + hw) ^ sx;
      a_off[t][ks] = ((wave & 1) * 4 + t * 2) * 512 + rbase + slot * 8;
      b_off[t][ks] = 4096 + ((wave >> 1) * 4 + t * 2) * 512 + rbase + slot * 8;
    }

  const unsigned short* Ag = A + (size_t)(m0 + sr) * K + sc * 8;
  const unsigned short* Bg = Bt + (size_t)(n0 + sr) * K + sc * 8;

  f32x16 acc[2][2];
#pragma unroll
  for (int i = 0; i < 2; i++)
#pragma unroll
    for (int j = 0; j < 2; j++) acc[i][j] = (f32x16)0.f;

  for (int k0 = 0; k0 < K; k0 += 32) {
    __syncthreads();
#pragma unroll
    for (int rd = 0; rd < 2; rd++) {
      const int ch = rd * 4 + wave;
      __builtin_amdgcn_global_load_lds(
          (const __attribute__((address_space(1))) void*)(Ag + (size_t)ch * 16 * K + k0),
          (__attribute__((address_space(3))) void*)&lds[ch * 512], 16, 0, 0);
      __builtin_amdgcn_global_load_lds(
          (const __attribute__((address_space(1))) void*)(Bg + (size_t)ch * 16 * K + k0),
          (__attribute__((address_space(3))) void*)&lds[4096 + ch * 512], 16, 0, 0);
    }
    __syncthreads();

    f16x8 af[2][2], bf[2][2];
#pragma unroll
    for (int t = 0; t < 2; t++)
#pragma unroll
      for (int ks = 0; ks < 2; ks++) {
        af[t][ks] = *(const f16x8*)&lds[a_off[t][ks]];
        bf[t][ks] = *(const f16x8*)&lds[b_off[t][ks]];
      }
#pragma unroll
    for (int ks = 0; ks < 2; ks++)
#pragma unroll
      for (int mi = 0; mi < 2; mi++)
#pragma unroll
        for (int ni = 0; ni < 2; ni++)
          acc[mi][ni] =
              __builtin_amdgcn_mfma_f32_32x32x16_f16(af[mi][ks], bf[ni][ks], acc[mi][ni], 0, 0, 0);
  }

  __syncthreads();  // staging region reused by epilogue repack

  if (EPI == EPI_F32_BIAS) {
    float* C = (float*)Cv;
#pragma unroll
    for (int ni = 0; ni < 2; ni++) {
      const int col = n0 + nb + ni * 32 + l31;
      const float bv = bias[col];
#pragma unroll
      for (int mi = 0; mi < 2; mi++)
#pragma unroll
        for (int reg = 0; reg < 16; reg++) {
          const int row = m0 + mb + mi * 32 + (reg & 3) + 8 * (reg >> 2) + 4 * hw;
          C[(size_t)row * N + col] = acc[mi][ni][reg] + bv;
        }
    }
  } else {
    // EPI_QKV: n0 < 2048 -> Q/K channels, transposed [channel][token] at Cv;
    //          n0 >= 2048 -> V, natural [token][channel] at Cv + 2048*M elems.
    unsigned short* C = (unsigned short*)Cv;
    const bool isT = (n0 < 2048);
    unsigned short* w = &lds[wave * 64 * LDS_LD];  // per-wave 64x64 repack region
#pragma unroll
    for (int mi = 0; mi < 2; mi++)
#pragma unroll
      for (int ni = 0; ni < 2; ni++)
#pragma unroll
        for (int reg = 0; reg < 16; reg++) {
          const int rl = mi * 32 + (reg & 3) + 8 * (reg >> 2) + 4 * hw;  // token
          const int cl = ni * 32 + l31;                                  // out channel
          if (isT)
            w[cl * LDS_LD + rl] = f2h(acc[mi][ni][reg]);
          else
            w[rl * LDS_LD + cl] = f2h(acc[mi][ni][reg]);
        }
#pragma unroll
    for (int p = 0; p < 8; p++) {
      const int a = p * 8 + (lane >> 3);
      const int b8 = (lane & 7) * 8;
      u16x4 lo = *(const u16x4*)&w[a * LDS_LD + b8];
      u16x4 hi = *(const u16x4*)&w[a * LDS_LD + b8 + 4];
      size_t gi;
      if (isT)
        gi = (size_t)(n0 + nb + a) * M + (m0 + mb + b8);  // qkt[ch][token]
      else
        gi = (size_t)2048 * 32768 + (size_t)(m0 + mb + a) * 1024 + (n0 - 2048 + nb + b8);
      *(u16x4*)&C[gi] = lo;
      *(u16x4*)&C[gi + 4] = hi;
    }
  }
}

// ---------------- attention stage 1: partial logits over 256-token chunks ----------------
// qkt: [2048][32768] f16 (rows 0..1023 Q channels, 1024..2047 K channels)
// pbuf: [128][16][64][64] f32 raw partial sums (no scale)
__global__ __launch_bounds__(256) void attn_logits(const unsigned short* __restrict__ qkt,
                                                   float* __restrict__ pbuf) {
  const int h = blockIdx.x, b = blockIdx.y, s = blockIdx.z;
  const int tid = threadIdx.x;
  const int wave = tid >> 6, lane = tid & 63;
  const int quad = lane >> 4, l15 = lane & 15;

  f32x4 acc[4];
#pragma unroll
  for (int t = 0; t < 4; t++) acc[t] = f32x4{0.f, 0.f, 0.f, 0.f};

  const unsigned short* qp =
      qkt + (size_t)(h * 64 + wave * 16 + l15) * 32768 + b * 4096 + s * 256 + quad * 8;
  const unsigned short* kp[4];
#pragma unroll
  for (int et = 0; et < 4; et++)
    kp[et] = qkt + (size_t)(1024 + h * 64 + et * 16 + l15) * 32768 + b * 4096 + s * 256 + quad * 8;

#pragma unroll 2
  for (int k0 = 0; k0 < 256; k0 += 32) {
    f16x8 aq = *(const f16x8*)(qp + k0);
#pragma unroll
    for (int et = 0; et < 4; et++) {
      f16x8 bk = *(const f16x8*)(kp[et] + k0);
      acc[et] = __builtin_amdgcn_mfma_f32_16x16x32_f16(aq, bk, acc[et], 0, 0, 0);
    }
  }

  float* pb = pbuf + ((size_t)(b * 16 + h) * 16 + s) * 4096;
#pragma unroll
  for (int et = 0; et < 4; et++)
#pragma unroll
    for (int rr = 0; rr < 4; rr++)
      pb[(wave * 16 + quad * 4 + rr) * 64 + et * 16 + l15] = acc[et][rr];
}

// ---------------- attention stage 2: reduce partials + softmax -> P f16 ----------------
// grid 128 = (b*16+h); thread tid: d = tid>>2, e-quarter = tid&3 (16 e's each)
__global__ __launch_bounds__(256) void attn_softmax(const float* __restrict__ pbuf,
                                                    unsigned short* __restrict__ pP) {
  const int bh = blockIdx.x;
  const int tid = threadIdx.x;
  const int d = tid >> 2, q4 = tid & 3;
  const float* pb = pbuf + (size_t)bh * 65536 + d * 64 + q4 * 16;

  float v[16];
#pragma unroll
  for (int i = 0; i < 16; i++) v[i] = 0.f;
  for (int s = 0; s < 16; s++) {
#pragma unroll
    for (int e4 = 0; e4 < 4; e4++) {
      float4 t = *(const float4*)(pb + s * 4096 + e4 * 4);
      v[e4 * 4 + 0] += t.x; v[e4 * 4 + 1] += t.y;
      v[e4 * 4 + 2] += t.z; v[e4 * 4 + 3] += t.w;
    }
  }
#pragma unroll
  for (int i = 0; i < 16; i++) v[i] *= 0.125f;  // SCALE = D^-0.5

  float m = v[0];
#pragma unroll
  for (int i = 1; i < 16; i++) m = fmaxf(m, v[i]);
  m = fmaxf(m, __shfl_xor(m, 1));  // threads d*4..d*4+3 are consecutive lanes
  m = fmaxf(m, __shfl_xor(m, 2));
  float sum = 0.f;
#pragma unroll
  for (int i = 0; i < 16; i++) {
    v[i] = __expf(v[i] - m);
    sum += v[i];
  }
  sum += __shfl_xor(sum, 1);
  sum += __shfl_xor(sum, 2);
  const float inv = 1.f / sum;

  unsigned short* pp = pP + (size_t)bh * 4096 + d * 64 + q4 * 16;
#pragma unroll
  for (int e4 = 0; e4 < 4; e4++) {
    u16x4 o;
    o.x = f2h(v[e4 * 4 + 0] * inv); o.y = f2h(v[e4 * 4 + 1] * inv);
    o.z = f2h(v[e4 * 4 + 2] * inv); o.w = f2h(v[e4 * 4 + 3] * inv);
    *(u16x4*)(pp + e4 * 4) = o;
  }
}

// ---------------- attention stage 3: O = P @ V over 256-token chunks ----------------
__global__ __launch_bounds__(256) void attn_pv(const unsigned short* __restrict__ pP,
                                               const unsigned short* __restrict__ vbuf,
                                               unsigned short* __restrict__ y) {
  const int h = blockIdx.x, b = blockIdx.y, s = blockIdx.z;
  const int tid = threadIdx.x;
  const int wave = tid >> 6, lane = tid & 63;
  const int quad = lane >> 4, l15 = lane & 15;
  const int bh = b * 16 + h;

  // A-frags straight from global: P[d = wave*16+l15][e = quad*8..], k-contiguous
  const unsigned short* pp = pP + (size_t)bh * 4096 + (wave * 16 + l15) * 64 + quad * 8;
  f16x8 pa0 = *(const f16x8*)(pp);
  f16x8 pa1 = *(const f16x8*)(pp + 32);

  const unsigned short* vb =
      vbuf + (size_t)(b * 4096 + s * 256 + l15) * 1024 + h * 64 + quad * 8;
  unsigned short* yb = y + (size_t)b * (4096 * 1024);

#pragma unroll 4
  for (int nt = 0; nt < 16; nt++) {
    const unsigned short* vp = vb + (size_t)nt * 16 * 1024;
    f16x8 v0 = *(const f16x8*)(vp);        // B[k=e][n=token] = V[token][e], natural layout
    f16x8 v1 = *(const f16x8*)(vp + 32);
    f32x4 o = f32x4{0.f, 0.f, 0.f, 0.f};
    o = __builtin_amdgcn_mfma_f32_16x16x32_f16(pa0, v0, o, 0, 0, 0);
    o = __builtin_amdgcn_mfma_f32_16x16x32_f16(pa1, v1, o, 0, 0, 0);
    const int n = s * 256 + nt * 16 + l15;
    const int nhi = n >> 10, nlo = n & 1023;
#pragma unroll
    for (int rr = 0; rr < 4; rr++) {
      const int d = wave * 16 + quad * 4 + rr;
      // transpose(0,2,1,3).reshape: (b,h,d,n) -> y[b][d*64 + h*4 + n/1024][n%1024]
      yb[(size_t)(d * 64 + h * 4 + nhi) * 1024 + nlo] = f2h(o[rr]);
    }
  }
}

extern "C" void kernel_launch(void* const* d_in, const int* in_sizes, int n_in, void* d_out,
                              int out_size, void* d_ws, size_t ws_size, hipStream_t stream) {
  (void)in_sizes; (void)n_in; (void)out_size; (void)ws_size;
  const float* x = (const float*)d_in[0];
  const float* Wq = (const float*)d_in[1];
  const float* Wk = (const float*)d_in[2];
  const float* Wv = (const float*)d_in[3];
  const float* Wp = (const float*)d_in[4];
  const float* bp = (const float*)d_in[5];

  char* ws = (char*)d_ws;
  unsigned short* xb = (unsigned short*)(ws);                        // 64 MB, x f16
  float* pbuf = (float*)(ws);                                        // 32 MB, aliases dead xb
  unsigned short* yb = xb;                                           // y aliases xb (after pbuf dead)
  unsigned short* qkt = (unsigned short*)(ws + (size_t)67108864);    // 128 MB, [2048][32768]
  unsigned short* pP = qkt;                                          // 0.5 MB, aliases dead qkt
  unsigned short* vbuf = (unsigned short*)(ws + (size_t)201326592);  // 64 MB, [32768][1024]
  unsigned short* wqkv = (unsigned short*)(ws + (size_t)268435456);  // 6 MB, [3072][1024]
  unsigned short* wp = (unsigned short*)(ws + (size_t)274726912);    // 2 MB

  cvt_f32_f16<<<32768, 256, 0, stream>>>(x, xb, 33554432);
  cvt4_f32_f16<<<dim3(1024, 4), 256, 0, stream>>>(Wq, Wk, Wv, Wp, wqkv, wqkv + 1048576,
                                                  wqkv + 2097152, wp);

  // fused Q,K,V projections: Q/K transposed [ch][token] -> qkt, V natural -> vbuf
  gemm_bt<EPI_QKV><<<dim3(24, 256), 256, 0, stream>>>(xb, wqkv, qkt, nullptr, 32768, 3072, 1024);

  // attention: partial logits -> reduce+softmax -> PV
  attn_logits<<<dim3(16, 8, 16), 256, 0, stream>>>(qkt, pbuf);
  attn_softmax<<<128, 256, 0, stream>>>(pbuf, pP);  // pP aliases qkt: dead after attn_logits
  attn_pv<<<dim3(16, 8, 16), 256, 0, stream>>>(pP, vbuf, yb);  // yb over pbuf: dead after softmax

  // output projection + bias, fp32 out
  gemm_bt<EPI_F32_BIAS><<<dim3(8, 256), 256, 0, stream>>>(yb, wp, (float*)d_out, bp, 32768, 1024, 1024);
}

// Round 5
// 693.251 us; speedup vs baseline: 1.0612x; 1.0612x over previous
//
#include <hip/hip_runtime.h>

// Self-attention (channel-attention variant), B=8 N=4096 C=1024 H=16 D=64.
// FP16 pipeline. cvt(x)->f16; cvt(W*) one dispatch; single QKV GEMM (N=3072,
// Q/K transposed [ch][token], V natural, 16x16x32 MFMA core - r3-verified);
// attention: partial logits (16,8,16) -> softmax (512 blocks) -> PV with
// LDS-repacked coalesced stores; final GEMM y@Wp^T + bp -> fp32 d_out.

typedef __attribute__((ext_vector_type(4))) float f32x4;
typedef __attribute__((ext_vector_type(8))) _Float16 f16x8;
typedef __attribute__((ext_vector_type(4))) unsigned short u16x4;
typedef __attribute__((ext_vector_type(8))) unsigned short u16x8;

__device__ __forceinline__ unsigned short f2h(float f) {
  union { _Float16 h; unsigned short u; } v;
  v.h = (_Float16)f;  // RNE
  return v.u;
}

__global__ void cvt_f32_f16(const float* __restrict__ in, unsigned short* __restrict__ out, int n) {
  int i = (blockIdx.x * blockDim.x + threadIdx.x) * 4;
  if (i >= n) return;
  float4 v = *(const float4*)(in + i);
  u16x4 o;
  o.x = f2h(v.x); o.y = f2h(v.y); o.z = f2h(v.z); o.w = f2h(v.w);
  *(u16x4*)(out + i) = o;
}

// 4 weight matrices (1M elems each) in one dispatch; blockIdx.y selects.
__global__ void cvt4_f32_f16(const float* __restrict__ s0, const float* __restrict__ s1,
                             const float* __restrict__ s2, const float* __restrict__ s3,
                             unsigned short* __restrict__ d0, unsigned short* __restrict__ d1,
                             unsigned short* __restrict__ d2, unsigned short* __restrict__ d3) {
  const float* src; unsigned short* dst;
  switch (blockIdx.y) {
    case 0: src = s0; dst = d0; break;
    case 1: src = s1; dst = d1; break;
    case 2: src = s2; dst = d2; break;
    default: src = s3; dst = d3; break;
  }
  int i = (blockIdx.x * blockDim.x + threadIdx.x) * 4;
  float4 v = *(const float4*)(src + i);
  u16x4 o;
  o.x = f2h(v.x); o.y = f2h(v.y); o.z = f2h(v.z); o.w = f2h(v.w);
  *(u16x4*)(dst + i) = o;
}

// ---------------- GEMM: C = A(MxK) * Bt(NxK)^T, fp16 in, 128x128 tile ----------------
// r3-verified core: 16x16x32 MFMA, staging XOR swizzle -> bank-clean frag b128 reads.
#define LDS_LD 68  // epilogue repack stride (u16)
enum { EPI_QKV = 0, EPI_F32_BIAS = 2 };

template <int EPI>
__global__ __launch_bounds__(256, 2) void gemm_bt(const unsigned short* __restrict__ A,
                                                  const unsigned short* __restrict__ Bt,
                                                  void* __restrict__ Cv,
                                                  const float* __restrict__ bias,
                                                  const int M, const int N, const int K) {
  __shared__ unsigned short lds[4 * 64 * LDS_LD];  // staging uses first 8192 u16
  const int tid = threadIdx.x;
  const int wave = tid >> 6, lane = tid & 63;
  const int quad = lane >> 4, l15 = lane & 15;
  const int m0 = blockIdx.y * 128, n0 = blockIdx.x * 128;
  const int mb = (wave & 1) * 64, nb = (wave >> 1) * 64;

  // staging: lane l fetches (row l>>2, 16B-piece (l&3)^((row>>1)&3)) -> XOR swizzle so
  // frag ds_read_b128 lands 2 lanes/bank (free) instead of 8-way.
  const int sr = lane >> 2;
  const int sc = (lane & 3) ^ ((sr >> 1) & 3);

  const int swz = quad ^ ((l15 >> 1) & 3);
  int a_off[4], b_off[4];
#pragma unroll
  for (int t = 0; t < 4; t++) {
    a_off[t] = ((mb >> 4) + t) * 512 + (l15 * 4 + swz) * 8;
    b_off[t] = 4096 + ((nb >> 4) + t) * 512 + (l15 * 4 + swz) * 8;
  }

  const unsigned short* Ag = A + (size_t)(m0 + sr) * K + sc * 8;
  const unsigned short* Bg = Bt + (size_t)(n0 + sr) * K + sc * 8;

  f32x4 acc[4][4];
#pragma unroll
  for (int i = 0; i < 4; i++)
#pragma unroll
    for (int j = 0; j < 4; j++) acc[i][j] = f32x4{0.f, 0.f, 0.f, 0.f};

  for (int k0 = 0; k0 < K; k0 += 32) {
    __syncthreads();
#pragma unroll
    for (int rd = 0; rd < 2; rd++) {
      const int ch = rd * 4 + wave;
      __builtin_amdgcn_global_load_lds(
          (const __attribute__((address_space(1))) void*)(Ag + (size_t)ch * 16 * K + k0),
          (__attribute__((address_space(3))) void*)&lds[ch * 512], 16, 0, 0);
      __builtin_amdgcn_global_load_lds(
          (const __attribute__((address_space(1))) void*)(Bg + (size_t)ch * 16 * K + k0),
          (__attribute__((address_space(3))) void*)&lds[4096 + ch * 512], 16, 0, 0);
    }
    __syncthreads();

    f16x8 af[4], bf[4];
#pragma unroll
    for (int t = 0; t < 4; t++) {
      af[t] = *(const f16x8*)&lds[a_off[t]];
      bf[t] = *(const f16x8*)&lds[b_off[t]];
    }
#pragma unroll
    for (int mi = 0; mi < 4; mi++)
#pragma unroll
      for (int ni = 0; ni < 4; ni++)
        acc[mi][ni] = __builtin_amdgcn_mfma_f32_16x16x32_f16(af[mi], bf[ni], acc[mi][ni], 0, 0, 0);
  }

  __syncthreads();  // staging region reused by epilogue repack

  if (EPI == EPI_F32_BIAS) {
    float* C = (float*)Cv;
#pragma unroll
    for (int ni = 0; ni < 4; ni++) {
      const int col = n0 + nb + ni * 16 + l15;
      const float bv = bias[col];
#pragma unroll
      for (int mi = 0; mi < 4; mi++)
#pragma unroll
        for (int rr = 0; rr < 4; rr++) {
          const int row = m0 + mb + mi * 16 + quad * 4 + rr;
          C[(size_t)row * N + col] = acc[mi][ni][rr] + bv;
        }
    }
  } else {
    // EPI_QKV: n0 < 2048 -> Q/K channels, transposed [channel][token] at Cv;
    //          n0 >= 2048 -> V, natural [token][channel] at Cv + 2048*M elems.
    unsigned short* C = (unsigned short*)Cv;
    const bool isT = (n0 < 2048);
    unsigned short* w = &lds[wave * 64 * LDS_LD];  // per-wave 64x64 repack region
#pragma unroll
    for (int mi = 0; mi < 4; mi++)
#pragma unroll
      for (int ni = 0; ni < 4; ni++)
#pragma unroll
        for (int rr = 0; rr < 4; rr++) {
          const int rl = mi * 16 + quad * 4 + rr;  // local row (token)
          const int cl = ni * 16 + l15;            // local col (out channel)
          if (isT)
            w[cl * LDS_LD + rl] = f2h(acc[mi][ni][rr]);
          else
            w[rl * LDS_LD + cl] = f2h(acc[mi][ni][rr]);
        }
#pragma unroll
    for (int p = 0; p < 8; p++) {
      const int a = p * 8 + (lane >> 3);
      const int b8 = (lane & 7) * 8;
      u16x4 lo = *(const u16x4*)&w[a * LDS_LD + b8];
      u16x4 hi = *(const u16x4*)&w[a * LDS_LD + b8 + 4];
      size_t gi;
      if (isT)
        gi = (size_t)(n0 + nb + a) * M + (m0 + mb + b8);  // qkt[ch][token]
      else
        gi = (size_t)2048 * 32768 + (size_t)(m0 + mb + a) * 1024 + (n0 - 2048 + nb + b8);
      *(u16x4*)&C[gi] = lo;
      *(u16x4*)&C[gi + 4] = hi;
    }
  }
}

// ---------------- attention stage 1: partial logits over 256-token chunks ----------------
// qkt: [2048][32768] f16 (rows 0..1023 Q channels, 1024..2047 K channels)
// pbuf: [128][16][64][64] f32 raw partial sums (no scale)
__global__ __launch_bounds__(256) void attn_logits(const unsigned short* __restrict__ qkt,
                                                   float* __restrict__ pbuf) {
  const int h = blockIdx.x, b = blockIdx.y, s = blockIdx.z;
  const int tid = threadIdx.x;
  const int wave = tid >> 6, lane = tid & 63;
  const int quad = lane >> 4, l15 = lane & 15;

  f32x4 acc[4];
#pragma unroll
  for (int t = 0; t < 4; t++) acc[t] = f32x4{0.f, 0.f, 0.f, 0.f};

  const unsigned short* qp =
      qkt + (size_t)(h * 64 + wave * 16 + l15) * 32768 + b * 4096 + s * 256 + quad * 8;
  const unsigned short* kp[4];
#pragma unroll
  for (int et = 0; et < 4; et++)
    kp[et] = qkt + (size_t)(1024 + h * 64 + et * 16 + l15) * 32768 + b * 4096 + s * 256 + quad * 8;

#pragma unroll 2
  for (int k0 = 0; k0 < 256; k0 += 32) {
    f16x8 aq = *(const f16x8*)(qp + k0);
#pragma unroll
    for (int et = 0; et < 4; et++) {
      f16x8 bk = *(const f16x8*)(kp[et] + k0);
      acc[et] = __builtin_amdgcn_mfma_f32_16x16x32_f16(aq, bk, acc[et], 0, 0, 0);
    }
  }

  float* pb = pbuf + ((size_t)(b * 16 + h) * 16 + s) * 4096;
#pragma unroll
  for (int et = 0; et < 4; et++)
#pragma unroll
    for (int rr = 0; rr < 4; rr++)
      pb[(wave * 16 + quad * 4 + rr) * 64 + et * 16 + l15] = acc[et][rr];
}

// ---------------- attention stage 2: reduce partials + softmax -> P f16 ----------------
// grid 512 = (bh, d-group of 16); thread t: d = dg*16 + (t>>4), e = (t&15)*4 .. +4
__global__ __launch_bounds__(256) void attn_softmax(const float* __restrict__ pbuf,
                                                    unsigned short* __restrict__ pP) {
  const int bh = blockIdx.x >> 2, dg = blockIdx.x & 3;
  const int t = threadIdx.x;
  const int d = dg * 16 + (t >> 4), e4 = t & 15;
  const float* pb = pbuf + (size_t)bh * 65536 + d * 64 + e4 * 4;

  float v[4] = {0.f, 0.f, 0.f, 0.f};
  for (int s = 0; s < 16; s++) {
    float4 tt = *(const float4*)(pb + s * 4096);
    v[0] += tt.x; v[1] += tt.y; v[2] += tt.z; v[3] += tt.w;
  }
#pragma unroll
  for (int i = 0; i < 4; i++) v[i] *= 0.125f;  // SCALE = D^-0.5

  // threads e4=0..15 for one d are 16 consecutive lanes -> xor-shuffle reduce width 16
  float m = fmaxf(fmaxf(v[0], v[1]), fmaxf(v[2], v[3]));
#pragma unroll
  for (int o = 1; o < 16; o <<= 1) m = fmaxf(m, __shfl_xor(m, o, 16));
  float sum = 0.f;
#pragma unroll
  for (int i = 0; i < 4; i++) {
    v[i] = __expf(v[i] - m);
    sum += v[i];
  }
#pragma unroll
  for (int o = 1; o < 16; o <<= 1) sum += __shfl_xor(sum, o, 16);
  const float inv = 1.f / sum;

  u16x4 o4;
  o4.x = f2h(v[0] * inv); o4.y = f2h(v[1] * inv);
  o4.z = f2h(v[2] * inv); o4.w = f2h(v[3] * inv);
  *(u16x4*)(pP + (size_t)bh * 4096 + d * 64 + e4 * 4) = o4;
}

// ---------------- attention stage 3: O = P @ V over 256-token chunks ----------------
// LDS-repacked epilogue: block's 64x256 O-tile staged in LDS, then 64 rows x 512B
// coalesced stores (vs 2B-scalar scattered stores at 64KB stride).
__global__ __launch_bounds__(256) void attn_pv(const unsigned short* __restrict__ pP,
                                               const unsigned short* __restrict__ vbuf,
                                               unsigned short* __restrict__ y) {
  __shared__ unsigned short tile[64 * 264];  // [d][256 tokens], stride 264 (33 KB)
  const int h = blockIdx.x, b = blockIdx.y, s = blockIdx.z;
  const int tid = threadIdx.x;
  const int wave = tid >> 6, lane = tid & 63;
  const int quad = lane >> 4, l15 = lane & 15;
  const int bh = b * 16 + h;

  // A-frags straight from global: P[d = wave*16+l15][e = quad*8..], k-contiguous
  const unsigned short* pp = pP + (size_t)bh * 4096 + (wave * 16 + l15) * 64 + quad * 8;
  f16x8 pa0 = *(const f16x8*)(pp);
  f16x8 pa1 = *(const f16x8*)(pp + 32);

  const unsigned short* vb =
      vbuf + (size_t)(b * 4096 + s * 256 + l15) * 1024 + h * 64 + quad * 8;

#pragma unroll 4
  for (int nt = 0; nt < 16; nt++) {
    const unsigned short* vp = vb + (size_t)nt * 16 * 1024;
    f16x8 v0 = *(const f16x8*)(vp);        // B[k=e][n=token] = V[token][e], natural layout
    f16x8 v1 = *(const f16x8*)(vp + 32);
    f32x4 o = f32x4{0.f, 0.f, 0.f, 0.f};
    o = __builtin_amdgcn_mfma_f32_16x16x32_f16(pa0, v0, o, 0, 0, 0);
    o = __builtin_amdgcn_mfma_f32_16x16x32_f16(pa1, v1, o, 0, 0, 0);
    const int ncol = nt * 16 + l15;
#pragma unroll
    for (int rr = 0; rr < 4; rr++)
      tile[(wave * 16 + quad * 4 + rr) * 264 + ncol] = f2h(o[rr]);
  }
  __syncthreads();

  // thread t: row d = t&63, col-chunk cc = t>>6 (64 u16 each); y row = d*64+h*4+(s>>2)
  const int d = tid & 63, cc = tid >> 6;
  const int R = d * 64 + h * 4 + (s >> 2);
  unsigned short* dst =
      y + (size_t)b * 4194304 + (size_t)R * 1024 + (s & 3) * 256 + cc * 64;
  const unsigned short* srcp = &tile[d * 264 + cc * 64];
#pragma unroll
  for (int i = 0; i < 8; i++)
    *(u16x8*)(dst + i * 8) = *(const u16x8*)(srcp + i * 8);
}

extern "C" void kernel_launch(void* const* d_in, const int* in_sizes, int n_in, void* d_out,
                              int out_size, void* d_ws, size_t ws_size, hipStream_t stream) {
  (void)in_sizes; (void)n_in; (void)out_size; (void)ws_size;
  const float* x = (const float*)d_in[0];
  const float* Wq = (const float*)d_in[1];
  const float* Wk = (const float*)d_in[2];
  const float* Wv = (const float*)d_in[3];
  const float* Wp = (const float*)d_in[4];
  const float* bp = (const float*)d_in[5];

  char* ws = (char*)d_ws;
  unsigned short* xb = (unsigned short*)(ws);                        // 64 MB, x f16
  float* pbuf = (float*)(ws);                                        // 32 MB, aliases dead xb
  unsigned short* yb = xb;                                           // y aliases xb (after pbuf dead)
  unsigned short* qkt = (unsigned short*)(ws + (size_t)67108864);    // 128 MB, [2048][32768]
  unsigned short* pP = qkt;                                          // 0.5 MB, aliases dead qkt
  unsigned short* vbuf = (unsigned short*)(ws + (size_t)201326592);  // 64 MB, [32768][1024]
  unsigned short* wqkv = (unsigned short*)(ws + (size_t)268435456);  // 6 MB, [3072][1024]
  unsigned short* wp = (unsigned short*)(ws + (size_t)274726912);    // 2 MB

  cvt_f32_f16<<<32768, 256, 0, stream>>>(x, xb, 33554432);
  cvt4_f32_f16<<<dim3(1024, 4), 256, 0, stream>>>(Wq, Wk, Wv, Wp, wqkv, wqkv + 1048576,
                                                  wqkv + 2097152, wp);

  // fused Q,K,V projections: Q/K transposed [ch][token] -> qkt, V natural -> vbuf
  gemm_bt<EPI_QKV><<<dim3(24, 256), 256, 0, stream>>>(xb, wqkv, qkt, nullptr, 32768, 3072, 1024);

  // attention: partial logits -> reduce+softmax -> PV
  attn_logits<<<dim3(16, 8, 16), 256, 0, stream>>>(qkt, pbuf);
  attn_softmax<<<512, 256, 0, stream>>>(pbuf, pP);  // pP aliases qkt: dead after attn_logits
  attn_pv<<<dim3(16, 8, 16), 256, 0, stream>>>(pP, vbuf, yb);  // yb over pbuf: dead after softmax

  // output projection + bias, fp32 out
  gemm_bt<EPI_F32_BIAS><<<dim3(8, 256), 256, 0, stream>>>(yb, wp, (float*)d_out, bp, 32768, 1024, 1024);
}